// Round 4
// baseline (430.752 us; speedup 1.0000x reference)
//
#include <hip/hip_runtime.h>

// R9: edge is latency-bound (DS 42%, VALU 23%, occupancy grid-capped at 39%).
//   - edge: grid 1024->1280 (5 blocks/CU x 32KB = full 160KB LDS pool)
//   - node: persistent blocks (stage 45KB weights ONCE, grid-stride groups),
//     acc tile as float4 b128 broadcasts (10 ds_read -> 3), wt relayout for read2.
//   - ptype parallelized (12 blocks).
// R8 lesson kept: NO VGPR cap on edge kernel; kk unroll 8.

#define NPB 8
#define EPW 8

__device__ inline void atomAddF(float* p, float v) {
#if defined(__HIP_PLATFORM_AMD__)
    unsafeAtomicAdd(p, v);
#else
    atomicAdd(p, v);
#endif
}

// ---------------------------------------------------------------------------
// Prepass 1: per-TYPE halves of the We2 GEMV.  12 blocks x 8 types.
// ---------------------------------------------------------------------------
__global__ void ptype_kernel(const float* __restrict__ emb,
                             const float* __restrict__ We2,
                             const float* __restrict__ be2,
                             float* __restrict__ Pt1, float* __restrict__ Pt2) {
    const int c = threadIdx.x & 31;
    const int t = blockIdx.x * 8 + (threadIdx.x >> 5);
    if (t < 95) {
        float p1 = 0.f, p2 = 0.f;
        for (int k = 0; k < 32; ++k) {
            const float z = emb[t * 32 + k];
            p1 = fmaf(z, We2[k * 32 + c], p1);
            p2 = fmaf(z, We2[(32 + k) * 32 + c], p2);
        }
        Pt1[t * 32 + c] = p1 + be2[c];
        Pt2[t * 32 + c] = p2;
    }
}

// ---------------------------------------------------------------------------
// Prepass 2: zero the accumulator + gather per-node P1/P2 from per-type tables.
// ---------------------------------------------------------------------------
__global__ void prep_zero(const int* __restrict__ nt,
                          const float* __restrict__ Pt1, const float* __restrict__ Pt2,
                          float* __restrict__ acc,
                          float* __restrict__ P1, float* __restrict__ P2, int N) {
    const int i = blockIdx.x * 256 + threadIdx.x;
    if (i < N * 320) acc[i] = 0.0f;
    if (i < N * 32) {
        const int n = i >> 5, c = i & 31;
        const int t = nt[n];
        P1[i] = Pt1[t * 32 + c];
        P2[i] = Pt2[t * 32 + c];
    }
}

// ---------------------------------------------------------------------------
// Edge kernel: one wave handles EPW=8 edges per pass.
// lane = (c = lane&31 channel, h = lane>>5 K-half). Half h accumulates
// k in [32h, 32h+32). Weights (Wd1,Wd2,Wd3,We3) staged once in 32KB LDS.
// VGPR note [R8]: do NOT cap VGPRs — caps pinned the allocator and spilled.
// kk unroll is 8 (not full) to bound scheduler-induced pressure.
// Grid note [R9]: launch 1280 blocks = 5 blocks/CU (LDS-pool-exact).
// ---------------------------------------------------------------------------
__global__ __launch_bounds__(256) void edge_kernel(
    const float* __restrict__ edge_attr,    // [E][64]
    const float* __restrict__ bond_dist,    // [E]
    const float* __restrict__ bond_vec,     // [E][3]
    const int*   __restrict__ src,
    const int*   __restrict__ dst,
    const float* __restrict__ Wd1, const float* __restrict__ bd1,
    const float* __restrict__ Wd2, const float* __restrict__ bd2,
    const float* __restrict__ Wd3, const float* __restrict__ bd3,
    const float* __restrict__ We3, const float* __restrict__ be3,
    const float* __restrict__ P1,           // [N][32]  (Zij src-half, bias folded)
    const float* __restrict__ P2,           // [N][32]  (Zij dst-half)
    float* __restrict__ acc,                // [N][10][32] fp32, pre-zeroed
    float* __restrict__ efeat,              // [E][32]
    int E)
{
    __shared__ float sW[4][64][32];   // 0:Wd1 1:Wd2 2:Wd3 3:We3  (32 KB)
    const int tid = threadIdx.x;
    for (int i = tid; i < 4 * 2048; i += 256) {
        const int m = i >> 11, r = i & 2047;
        const float* W = (m == 0) ? Wd1 : (m == 1) ? Wd2 : (m == 2) ? Wd3 : We3;
        sW[m][r >> 5][r & 31] = W[r];
    }
    __syncthreads();

    const int lane = tid & 63;
    const int c = lane & 31;
    const int h = lane >> 5;
    const float bd1r = bd1[c], bd2r = bd2[c], bd3r = bd3[c], be3r = be3[c];
    const float* wbase = &sW[0][h * 32][c];   // + kk*32 (+ m*2048) -> imm offsets

    const int wid = __builtin_amdgcn_readfirstlane((blockIdx.x * 256 + tid) >> 6);
    const int nw = gridDim.x * 4;
    const int ngroups = (E + EPW - 1) / EPW;

    for (int g = wid; g < ngroups; g += nw) {
        const int base = g * EPW;

        // x rows: lane l of edge j's row -> one coalesced 256B load per edge
        float xr[EPW];
#pragma unroll
        for (int j = 0; j < EPW; ++j) {
            int e = base + j; if (e >= E) e = E - 1;
            xr[j] = edge_attr[(size_t)e * 64 + lane];
        }

        float A0[EPW], A1[EPW], A2[EPW], A3[EPW];
#pragma unroll
        for (int j = 0; j < EPW; ++j) { A0[j] = 0.f; A1[j] = 0.f; A2[j] = 0.f; A3[j] = 0.f; }

#pragma unroll 8
        for (int kk = 0; kk < 32; ++kk) {
            const float w0 = wbase[kk * 32];           // sW[0][h*32+kk][c]
            const float w1 = wbase[kk * 32 + 2048];
            const float w2 = wbase[kk * 32 + 4096];
            const float w3 = wbase[kk * 32 + 6144];
#pragma unroll
            for (int j = 0; j < EPW; ++j) {
                const float xb = __shfl(xr[j], kk, 32);  // half0: x[kk], half1: x[32+kk]
                A0[j] = fmaf(xb, w0, A0[j]);
                A1[j] = fmaf(xb, w1, A1[j]);
                A2[j] = fmaf(xb, w2, A2[j]);
                A3[j] = fmaf(xb, w3, A3[j]);
            }
        }

        // Epilogue over 4 pairs: half0 handles edge base+jj, half1 handles base+jj+4.
#pragma unroll
        for (int jj = 0; jj < 4; ++jj) {
            // exchange cross-half partials: send the partial of the OTHER half's edge
            const float sd0 = h ? A0[jj] : A0[jj + 4];
            const float sd1 = h ? A1[jj] : A1[jj + 4];
            const float sd2 = h ? A2[jj] : A2[jj + 4];
            const float sd3 = h ? A3[jj] : A3[jj + 4];
            const float mn0 = h ? A0[jj + 4] : A0[jj];
            const float mn1 = h ? A1[jj + 4] : A1[jj];
            const float mn2 = h ? A2[jj + 4] : A2[jj];
            const float mn3 = h ? A3[jj + 4] : A3[jj];
            const float t0 = mn0 + __shfl_xor(sd0, 32);
            const float t1 = mn1 + __shfl_xor(sd1, 32);
            const float t2 = mn2 + __shfl_xor(sd2, 32);
            const float t3 = mn3 + __shfl_xor(sd3, 32);

            const int e = base + jj + 4 * h;
            const bool val = (e < E);
            const int ec = val ? e : (E - 1);

            const float d = bond_dist[ec];
            const float C = (d <= 5.0f) ? 0.5f * (cosf(3.14159265358979323846f * d / 5.0f) + 1.0f) : 0.0f;
            float v0 = bond_vec[3 * (size_t)ec + 0];
            float v1 = bond_vec[3 * (size_t)ec + 1];
            float v2 = bond_vec[3 * (size_t)ec + 2];
            const float inv = 1.0f / sqrtf(v0 * v0 + v1 * v1 + v2 * v2);
            v0 *= inv; v1 *= inv; v2 *= inv;
            const float tr3 = (v0 * v0 + v1 * v1 + v2 * v2) * (1.0f / 3.0f);
            const float y00 = v0 * v0 - tr3, y11 = v1 * v1 - tr3, y22 = v2 * v2 - tr3;
            const float y01 = v0 * v1, y02 = v0 * v2, y12 = v1 * v2;

            const int si = src[ec], di = dst[ec];
            const float az = P1[(size_t)si * 32 + c] + P2[(size_t)di * 32 + c];

            const float a1v = t0 + bd1r;
            const float a2v = t1 + bd2r;
            const float a3v = t2 + bd3r;
            const float a4v = t3 + be3r;
            const float w1v = a1v * C, w2v = a2v * C, w3v = a3v * C;
            const float fI = az * w1v, fA = az * w2v, fS = az * w3v;

            if (val) {
                efeat[(size_t)e * 32 + c] = a4v;
                float* ap = acc + (size_t)di * 320 + c;
                atomAddF(ap,       fI);
                atomAddF(ap + 32,  fA * v0);
                atomAddF(ap + 64,  fA * v1);
                atomAddF(ap + 96,  fA * v2);
                atomAddF(ap + 128, fS * y00);
                atomAddF(ap + 160, fS * y01);
                atomAddF(ap + 192, fS * y02);
                atomAddF(ap + 224, fS * y11);
                atomAddF(ap + 256, fS * y12);
                atomAddF(ap + 288, fS * y22);
            }
        }
    }
}

// ---------------------------------------------------------------------------
// Node kernel [R9]: PERSISTENT blocks — stage 45KB of weights once, then
// grid-stride over node groups (NPB=8 nodes each). Mixing-loop acc reads are
// 3 uniform ds_read_b128 broadcasts per k (was 10 scalar b32); wt relayout
// [k][3][32] so the 3 weight reads pair into ds_read2_b32 range.
// LDS ~60KB -> 2 blocks/CU; grid 512.
// ---------------------------------------------------------------------------
__global__ __launch_bounds__(256) void node_kernel(
    const float* __restrict__ acc,          // [N][10][32]
    const float* __restrict__ Wt0, const float* __restrict__ Wt1, const float* __restrict__ Wt2,
    const float* __restrict__ Ws1, const float* __restrict__ bs1,
    const float* __restrict__ Ws2, const float* __restrict__ bs2,
    const float* __restrict__ lng, const float* __restrict__ lnb,
    float* __restrict__ xout,               // [N][32][3][3]
    int N, int ngroups)
{
    __shared__ float wtS[32][96];           // [k][m*32+u]
    __shared__ float ws1[32][64];
    __shared__ float ws2[64][96];
    __shared__ float sb1[64], sb2[96], sg[32], sbv[32];
    __shared__ float4 accS4[NPB][32][3];    // [ln][k(channel)][{c0,a0,a1,a2|s00,s01,s02,s11|s12,s22,-,-}]
    __shared__ float nrmS[NPB][32];
    __shared__ float h1S[NPB][64];

    const int tid = threadIdx.x;
    for (int i = tid; i < 1024; i += 256) {
        const int k = i >> 5, u = i & 31;
        wtS[k][u]      = Wt0[i];
        wtS[k][32 + u] = Wt1[i];
        wtS[k][64 + u] = Wt2[i];
    }
    for (int i = tid; i < 2048; i += 256) ws1[i >> 6][i & 63] = Ws1[i];
    for (int i = tid; i < 6144; i += 256) ws2[i / 96][i % 96] = Ws2[i];
    if (tid < 64) sb1[tid] = bs1[tid];
    if (tid < 96) sb2[tid] = bs2[tid];
    if (tid < 32) { sg[tid] = lng[tid]; sbv[tid] = lnb[tid]; }
    __syncthreads();

    const int ln_ = tid >> 5, u = tid & 31;

    for (int g = blockIdx.x; g < ngroups; g += gridDim.x) {
        const int n = g * NPB + ln_;
        const bool valid = n < N;

        float c0 = 0, a0 = 0, a1 = 0, a2 = 0, s00 = 0, s01 = 0, s02 = 0, s11 = 0, s12 = 0, s22 = 0;
        if (valid) {
            const float* ap = acc + (size_t)n * 320 + u;
            c0 = ap[0];  a0 = ap[32];  a1 = ap[64];  a2 = ap[96];
            s00 = ap[128]; s01 = ap[160]; s02 = ap[192];
            s11 = ap[224]; s12 = ap[256]; s22 = ap[288];
        }
        accS4[ln_][u][0] = make_float4(c0, a0, a1, a2);
        accS4[ln_][u][1] = make_float4(s00, s01, s02, s11);
        accS4[ln_][u][2] = make_float4(s12, s22, 0.f, 0.f);

        const float m00 = c0 + s00, m11 = c0 + s11, m22 = c0 + s22;
        float nrm = m00 * m00 + m11 * m11 + m22 * m22
                  + 2.0f * (s01 * s01 + a2 * a2 + s02 * s02 + a1 * a1 + s12 * s12 + a0 * a0);

        float sum = nrm;
#pragma unroll
        for (int o = 16; o >= 1; o >>= 1) sum += __shfl_xor(sum, o, 32);
        const float mu = sum * (1.0f / 32.0f);
        const float dv = nrm - mu;
        float vs = dv * dv;
#pragma unroll
        for (int o = 16; o >= 1; o >>= 1) vs += __shfl_xor(vs, o, 32);
        const float var = vs * (1.0f / 32.0f);
        const float nl = dv * rsqrtf(var + 1e-5f) * sg[u] + sbv[u];
        nrmS[ln_][u] = nl;
        __syncthreads();

        float h1a = sb1[u], h1b = sb1[u + 32];
#pragma unroll
        for (int k = 0; k < 32; ++k) {
            const float x = nrmS[ln_][k];
            h1a += x * ws1[k][u];
            h1b += x * ws1[k][u + 32];
        }
        h1a = h1a / (1.0f + __expf(-h1a));
        h1b = h1b / (1.0f + __expf(-h1b));
        h1S[ln_][u] = h1a; h1S[ln_][u + 32] = h1b;
        __syncthreads();

        float f0 = sb2[3 * u], f1 = sb2[3 * u + 1], f2 = sb2[3 * u + 2];
#pragma unroll
        for (int k = 0; k < 64; ++k) {
            const float hh = h1S[ln_][k];
            f0 += hh * ws2[k][3 * u];
            f1 += hh * ws2[k][3 * u + 1];
            f2 += hh * ws2[k][3 * u + 2];
        }
        f0 = f0 / (1.0f + __expf(-f0));
        f1 = f1 / (1.0f + __expf(-f1));
        f2 = f2 / (1.0f + __expf(-f2));

        float m0 = 0, ma0 = 0, ma1 = 0, ma2 = 0;
        float ms00 = 0, ms01 = 0, ms02 = 0, ms11 = 0, ms12 = 0, ms22 = 0;
#pragma unroll
        for (int k = 0; k < 32; ++k) {
            const float w0 = wtS[k][u], w1 = wtS[k][32 + u], w2 = wtS[k][64 + u];
            const float4 q0 = accS4[ln_][k][0];
            const float4 q1 = accS4[ln_][k][1];
            const float4 q2 = accS4[ln_][k][2];
            m0   += q0.x * w0;
            ma0  += q0.y * w1;
            ma1  += q0.z * w1;
            ma2  += q0.w * w1;
            ms00 += q1.x * w2;
            ms01 += q1.y * w2;
            ms02 += q1.z * w2;
            ms11 += q1.w * w2;
            ms12 += q2.x * w2;
            ms22 += q2.y * w2;
        }
        if (valid) {
            float* xp = xout + (size_t)n * 288 + u * 9;
            xp[0] = f0 * m0 + f2 * ms00;
            xp[1] = f1 * (-ma2) + f2 * ms01;
            xp[2] = f1 * ( ma1) + f2 * ms02;
            xp[3] = f1 * ( ma2) + f2 * ms01;
            xp[4] = f0 * m0 + f2 * ms11;
            xp[5] = f1 * (-ma0) + f2 * ms12;
            xp[6] = f1 * (-ma1) + f2 * ms02;
            xp[7] = f1 * ( ma0) + f2 * ms12;
            xp[8] = f0 * m0 + f2 * ms22;
        }
        __syncthreads();   // accS4/nrmS/h1S reused next group
    }
}

extern "C" void kernel_launch(void* const* d_in, const int* in_sizes, int n_in,
                              void* d_out, int out_size, void* d_ws, size_t ws_size,
                              hipStream_t stream) {
    const int N = in_sizes[0];
    const int E = in_sizes[2];

    // Workspace layout (fp32): acc N*320 | P1 N*32 | P2 N*32 | Pt1 95*32 | Pt2 95*32
    float* acc = (float*)d_ws;
    float* P1  = acc + (size_t)N * 320;
    float* P2  = P1 + (size_t)N * 32;
    float* Pt1 = P2 + (size_t)N * 32;
    float* Pt2 = Pt1 + 95 * 32;

    float* xout  = (float*)d_out;              // [N][32][3][3] f32
    float* efeat = xout + (size_t)N * 288;     // [E][32] f32

    ptype_kernel<<<12, 256, 0, stream>>>(
        (const float*)d_in[6], (const float*)d_in[13], (const float*)d_in[14], Pt1, Pt2);

    prep_zero<<<(N * 320 + 255) / 256, 256, 0, stream>>>(
        (const int*)d_in[0], Pt1, Pt2, acc, P1, P2, N);

    edge_kernel<<<1280, 256, 0, stream>>>(
        (const float*)d_in[1], (const float*)d_in[2], (const float*)d_in[3],
        (const int*)d_in[4], (const int*)d_in[5],
        (const float*)d_in[7],  (const float*)d_in[8],
        (const float*)d_in[9],  (const float*)d_in[10],
        (const float*)d_in[11], (const float*)d_in[12],
        (const float*)d_in[15], (const float*)d_in[16],
        P1, P2, acc, efeat, E);

    const int ngroups = (N + NPB - 1) / NPB;
    node_kernel<<<512, 256, 0, stream>>>(
        acc,
        (const float*)d_in[17], (const float*)d_in[18], (const float*)d_in[19],
        (const float*)d_in[20], (const float*)d_in[21],
        (const float*)d_in[22], (const float*)d_in[23],
        (const float*)d_in[24], (const float*)d_in[25],
        xout, N, ngroups);
}

// Round 5
// 429.068 us; speedup vs baseline: 1.0039x; 1.0039x over previous
//
#include <hip/hip_runtime.h>

// R10: edge was latency-bound on the DS chain (pipes ~85% idle; occupancy bump
// was neutral). Edge v2: weights in 128 VGPRs/lane (zero in-loop weight reads),
// x-rows staged per-wave in 2KB LDS, consumed as uniform ds_read_b128 broadcasts.
// DS/group 400->68. Node v2: barrier-free (1 node per half-wave, shfl instead of
// LDS round-trips for nrm/h1), packed float2/float4 weight reads.
// R8 lesson kept: NO VGPR cap anywhere.

#define EPW 8

__device__ inline void atomAddF(float* p, float v) {
#if defined(__HIP_PLATFORM_AMD__)
    unsafeAtomicAdd(p, v);
#else
    atomicAdd(p, v);
#endif
}

// ---------------------------------------------------------------------------
// Prepass 1: per-TYPE halves of the We2 GEMV.  12 blocks x 8 types.
// ---------------------------------------------------------------------------
__global__ void ptype_kernel(const float* __restrict__ emb,
                             const float* __restrict__ We2,
                             const float* __restrict__ be2,
                             float* __restrict__ Pt1, float* __restrict__ Pt2) {
    const int c = threadIdx.x & 31;
    const int t = blockIdx.x * 8 + (threadIdx.x >> 5);
    if (t < 95) {
        float p1 = 0.f, p2 = 0.f;
        for (int k = 0; k < 32; ++k) {
            const float z = emb[t * 32 + k];
            p1 = fmaf(z, We2[k * 32 + c], p1);
            p2 = fmaf(z, We2[(32 + k) * 32 + c], p2);
        }
        Pt1[t * 32 + c] = p1 + be2[c];
        Pt2[t * 32 + c] = p2;
    }
}

// ---------------------------------------------------------------------------
// Prepass 2: zero the accumulator + gather per-node P1/P2 from per-type tables.
// ---------------------------------------------------------------------------
__global__ void prep_zero(const int* __restrict__ nt,
                          const float* __restrict__ Pt1, const float* __restrict__ Pt2,
                          float* __restrict__ acc,
                          float* __restrict__ P1, float* __restrict__ P2, int N) {
    const int i = blockIdx.x * 256 + threadIdx.x;
    if (i < N * 320) acc[i] = 0.0f;
    if (i < N * 32) {
        const int n = i >> 5, c = i & 31;
        const int t = nt[n];
        P1[i] = Pt1[t * 32 + c];
        P2[i] = Pt2[t * 32 + c];
    }
}

// ---------------------------------------------------------------------------
// Edge kernel v2 [R10]:
//  - lane = (c = lane&31 channel, h = lane>>5 K-half)
//  - weight columns for (c,h) in 128 VGPRs, loaded ONCE per kernel
//  - per group: stage 8 edge rows (2KB) in per-wave LDS via float4 loads +
//    2 ds_write_b128; k-loop reads uniform ds_read_b128 broadcasts (64/group)
//  - NO __syncthreads anywhere (per-wave LDS region, same-wave RAW only)
//  - per-pair scalars hoisted above the k-loop to hide their latency
// ---------------------------------------------------------------------------
__global__ __launch_bounds__(256) void edge_kernel(
    const float* __restrict__ edge_attr,    // [E][64]
    const float* __restrict__ bond_dist,    // [E]
    const float* __restrict__ bond_vec,     // [E][3]
    const int*   __restrict__ src,
    const int*   __restrict__ dst,
    const float* __restrict__ Wd1, const float* __restrict__ bd1,
    const float* __restrict__ Wd2, const float* __restrict__ bd2,
    const float* __restrict__ Wd3, const float* __restrict__ bd3,
    const float* __restrict__ We3, const float* __restrict__ be3,
    const float* __restrict__ P1,           // [N][32]  (Zij src-half, bias folded)
    const float* __restrict__ P2,           // [N][32]  (Zij dst-half)
    float* __restrict__ acc,                // [N][10][32] fp32, pre-zeroed
    float* __restrict__ efeat,              // [E][32]
    int E)
{
    __shared__ float4 sX[4][8][16];         // per-wave x-tile: 8 edges x 64 floats

    const int tid  = threadIdx.x;
    const int lane = tid & 63;
    const int c    = lane & 31;
    const int h    = lane >> 5;
    const int wv   = tid >> 6;

    // --- weight columns -> registers (static indices via full unroll) ---
    float w0r[32], w1r[32], w2r[32], w3r[32];
#pragma unroll
    for (int kk = 0; kk < 32; ++kk) {
        const int row = (h << 5) + kk;
        w0r[kk] = Wd1[row * 32 + c];
        w1r[kk] = Wd2[row * 32 + c];
        w2r[kk] = Wd3[row * 32 + c];
        w3r[kk] = We3[row * 32 + c];
    }
    const float bd1r = bd1[c], bd2r = bd2[c], bd3r = bd3[c], be3r = be3[c];

    float4 (*sXw)[16] = sX[wv];

    const int wid = (blockIdx.x * 256 + tid) >> 6;
    const int nw  = gridDim.x * 4;
    const int ngroups = (E + EPW - 1) / EPW;

    for (int g = wid; g < ngroups; g += nw) {
        const int base = g * EPW;

        // hoisted per-pair scalars (latency hidden under the FMA loop)
        int si4[4], di4[4];
        float dd[4], vx[4], vy[4], vz[4];
#pragma unroll
        for (int jj = 0; jj < 4; ++jj) {
            int e = base + jj + (h << 2); if (e >= E) e = E - 1;
            si4[jj] = src[e]; di4[jj] = dst[e];
            dd[jj]  = bond_dist[e];
            vx[jj]  = bond_vec[3 * (size_t)e + 0];
            vy[jj]  = bond_vec[3 * (size_t)e + 1];
            vz[jj]  = bond_vec[3 * (size_t)e + 2];
        }

        // stage 8 edge rows into per-wave LDS (coalesced float4, no barrier)
        {
            int ea = base + (lane >> 4);     if (ea >= E) ea = E - 1;
            int eb = base + 4 + (lane >> 4); if (eb >= E) eb = E - 1;
            const float4 xa = *(const float4*)&edge_attr[(size_t)ea * 64 + (lane & 15) * 4];
            const float4 xb = *(const float4*)&edge_attr[(size_t)eb * 64 + (lane & 15) * 4];
            sXw[lane >> 4][lane & 15]     = xa;
            sXw[4 + (lane >> 4)][lane & 15] = xb;
        }

        float A0[EPW], A1[EPW], A2[EPW], A3[EPW];
#pragma unroll
        for (int j = 0; j < EPW; ++j) { A0[j] = 0.f; A1[j] = 0.f; A2[j] = 0.f; A3[j] = 0.f; }

        // k-loop: half h consumes float4s [h*8 .. h*8+7] of each edge row.
        // Uniform address per half -> broadcast read, 2-way across halves = free.
#pragma unroll
        for (int kq = 0; kq < 8; ++kq) {
            const int k0 = kq * 4;
#pragma unroll
            for (int j = 0; j < EPW; ++j) {
                const float4 xq = sXw[j][(h << 3) + kq];
                A0[j] = fmaf(xq.x, w0r[k0 + 0], A0[j]);
                A0[j] = fmaf(xq.y, w0r[k0 + 1], A0[j]);
                A0[j] = fmaf(xq.z, w0r[k0 + 2], A0[j]);
                A0[j] = fmaf(xq.w, w0r[k0 + 3], A0[j]);
                A1[j] = fmaf(xq.x, w1r[k0 + 0], A1[j]);
                A1[j] = fmaf(xq.y, w1r[k0 + 1], A1[j]);
                A1[j] = fmaf(xq.z, w1r[k0 + 2], A1[j]);
                A1[j] = fmaf(xq.w, w1r[k0 + 3], A1[j]);
                A2[j] = fmaf(xq.x, w2r[k0 + 0], A2[j]);
                A2[j] = fmaf(xq.y, w2r[k0 + 1], A2[j]);
                A2[j] = fmaf(xq.z, w2r[k0 + 2], A2[j]);
                A2[j] = fmaf(xq.w, w2r[k0 + 3], A2[j]);
                A3[j] = fmaf(xq.x, w3r[k0 + 0], A3[j]);
                A3[j] = fmaf(xq.y, w3r[k0 + 1], A3[j]);
                A3[j] = fmaf(xq.z, w3r[k0 + 2], A3[j]);
                A3[j] = fmaf(xq.w, w3r[k0 + 3], A3[j]);
            }
        }

        // az loads issue first in the epilogue (src/dst long since arrived)
        float az4[4];
#pragma unroll
        for (int jj = 0; jj < 4; ++jj)
            az4[jj] = P1[(size_t)si4[jj] * 32 + c] + P2[(size_t)di4[jj] * 32 + c];

        // Epilogue: half0 handles edge base+jj, half1 handles base+jj+4.
#pragma unroll
        for (int jj = 0; jj < 4; ++jj) {
            const float sd0 = h ? A0[jj] : A0[jj + 4];
            const float sd1 = h ? A1[jj] : A1[jj + 4];
            const float sd2 = h ? A2[jj] : A2[jj + 4];
            const float sd3 = h ? A3[jj] : A3[jj + 4];
            const float mn0 = h ? A0[jj + 4] : A0[jj];
            const float mn1 = h ? A1[jj + 4] : A1[jj];
            const float mn2 = h ? A2[jj + 4] : A2[jj];
            const float mn3 = h ? A3[jj + 4] : A3[jj];
            const float t0 = mn0 + __shfl_xor(sd0, 32);
            const float t1 = mn1 + __shfl_xor(sd1, 32);
            const float t2 = mn2 + __shfl_xor(sd2, 32);
            const float t3 = mn3 + __shfl_xor(sd3, 32);

            const int e = base + jj + 4 * h;
            const bool val = (e < E);

            const float d = dd[jj];
            const float C = (d <= 5.0f) ? 0.5f * (cosf(3.14159265358979323846f * d / 5.0f) + 1.0f) : 0.0f;
            float v0 = vx[jj], v1 = vy[jj], v2 = vz[jj];
            const float inv = 1.0f / sqrtf(v0 * v0 + v1 * v1 + v2 * v2);
            v0 *= inv; v1 *= inv; v2 *= inv;
            const float tr3 = (v0 * v0 + v1 * v1 + v2 * v2) * (1.0f / 3.0f);
            const float y00 = v0 * v0 - tr3, y11 = v1 * v1 - tr3, y22 = v2 * v2 - tr3;
            const float y01 = v0 * v1, y02 = v0 * v2, y12 = v1 * v2;

            const float az = az4[jj];
            const float a1v = t0 + bd1r;
            const float a2v = t1 + bd2r;
            const float a3v = t2 + bd3r;
            const float a4v = t3 + be3r;
            const float w1v = a1v * C, w2v = a2v * C, w3v = a3v * C;
            const float fI = az * w1v, fA = az * w2v, fS = az * w3v;

            if (val) {
                efeat[(size_t)e * 32 + c] = a4v;
                float* ap = acc + (size_t)di4[jj] * 320 + c;
                atomAddF(ap,       fI);
                atomAddF(ap + 32,  fA * v0);
                atomAddF(ap + 64,  fA * v1);
                atomAddF(ap + 96,  fA * v2);
                atomAddF(ap + 128, fS * y00);
                atomAddF(ap + 160, fS * y01);
                atomAddF(ap + 192, fS * y02);
                atomAddF(ap + 224, fS * y11);
                atomAddF(ap + 256, fS * y12);
                atomAddF(ap + 288, fS * y22);
            }
        }
    }
}

// ---------------------------------------------------------------------------
// Node kernel v2 [R10]: barrier-free main loop. Each half-wave (32 lanes = 32
// channels) owns one node end-to-end; nrm/h1 move via width-32 shuffles (no
// LDS round-trips, no __syncthreads). Weights staged once, packed:
//   wtp  [k][u] float4 {Wt0,Wt1,Wt2,-}   -> 1 b128/k   (was 3 b32)
//   ws1p [k][u] float2 {W[k][u],W[k][u+32]} -> 1 b64/k  (was 2 b32)
//   ws2p [k][u] float4 {W[k][3u..3u+2],-}  -> 1 b128/k  (was 3 b32)
// acc tile per half-wave in LDS as 3x float4 (uniform broadcast reads in mix).
// ---------------------------------------------------------------------------
__global__ __launch_bounds__(256) void node_kernel(
    const float* __restrict__ acc,          // [N][10][32]
    const float* __restrict__ Wt0, const float* __restrict__ Wt1, const float* __restrict__ Wt2,
    const float* __restrict__ Ws1, const float* __restrict__ bs1,
    const float* __restrict__ Ws2, const float* __restrict__ bs2,
    const float* __restrict__ lng, const float* __restrict__ lnb,
    float* __restrict__ xout,               // [N][32][3][3]
    int N)
{
    __shared__ float4 wtp[32][32];          // 16 KB
    __shared__ float2 ws1p[32][32];         // 8 KB
    __shared__ float4 ws2p[64][32];         // 32 KB
    __shared__ float4 accS4[8][32][3];      // 12 KB (per half-wave private)
    __shared__ float2 sb1p[32];
    __shared__ float4 sb2p[32];
    __shared__ float  sg[32], sbv[32];

    const int tid = threadIdx.x;
    for (int i = tid; i < 1024; i += 256) {
        const int k = i >> 5, u = i & 31;
        wtp[k][u]  = make_float4(Wt0[i], Wt1[i], Wt2[i], 0.f);
        ws1p[k][u] = make_float2(Ws1[k * 64 + u], Ws1[k * 64 + 32 + u]);
    }
    for (int i = tid; i < 2048; i += 256) {
        const int k = i >> 5, u = i & 31;
        ws2p[k][u] = make_float4(Ws2[k * 96 + 3 * u], Ws2[k * 96 + 3 * u + 1],
                                 Ws2[k * 96 + 3 * u + 2], 0.f);
    }
    if (tid < 32) {
        sb1p[tid] = make_float2(bs1[tid], bs1[tid + 32]);
        sb2p[tid] = make_float4(bs2[3 * tid], bs2[3 * tid + 1], bs2[3 * tid + 2], 0.f);
        sg[tid] = lng[tid]; sbv[tid] = lnb[tid];
    }
    __syncthreads();   // the only barrier

    const int hw = tid >> 5, u = tid & 31;
    const int stride = gridDim.x * 8;

    for (int n = blockIdx.x * 8 + hw; n < N; n += stride) {
        const float* ap = acc + (size_t)n * 320 + u;
        const float c0 = ap[0],   a0 = ap[32],  a1 = ap[64],  a2 = ap[96];
        const float s00 = ap[128], s01 = ap[160], s02 = ap[192];
        const float s11 = ap[224], s12 = ap[256], s22 = ap[288];

        accS4[hw][u][0] = make_float4(c0, a0, a1, a2);
        accS4[hw][u][1] = make_float4(s00, s01, s02, s11);
        accS4[hw][u][2] = make_float4(s12, s22, 0.f, 0.f);

        const float m00 = c0 + s00, m11 = c0 + s11, m22 = c0 + s22;
        float nrm = m00 * m00 + m11 * m11 + m22 * m22
                  + 2.0f * (s01 * s01 + a2 * a2 + s02 * s02 + a1 * a1 + s12 * s12 + a0 * a0);

        float sum = nrm;
#pragma unroll
        for (int o = 16; o >= 1; o >>= 1) sum += __shfl_xor(sum, o, 32);
        const float mu = sum * (1.0f / 32.0f);
        const float dv = nrm - mu;
        float vs = dv * dv;
#pragma unroll
        for (int o = 16; o >= 1; o >>= 1) vs += __shfl_xor(vs, o, 32);
        const float var = vs * (1.0f / 32.0f);
        const float nl = dv * rsqrtf(var + 1e-5f) * sg[u] + sbv[u];

        // h1 = silu(nrm @ Ws1 + bs1): nl broadcast via shfl, no LDS round-trip
        const float2 b1 = sb1p[u];
        float h1a = b1.x, h1b = b1.y;
#pragma unroll
        for (int k = 0; k < 32; ++k) {
            const float x = __shfl(nl, k, 32);
            const float2 wq = ws1p[k][u];
            h1a = fmaf(x, wq.x, h1a);
            h1b = fmaf(x, wq.y, h1b);
        }
        h1a = h1a / (1.0f + __expf(-h1a));
        h1b = h1b / (1.0f + __expf(-h1b));

        // f = silu(h1 @ Ws2 + bs2): h1 broadcast via shfl
        const float4 b2 = sb2p[u];
        float f0 = b2.x, f1 = b2.y, f2 = b2.z;
#pragma unroll
        for (int k = 0; k < 32; ++k) {
            const float hh = __shfl(h1a, k, 32);
            const float4 wq = ws2p[k][u];
            f0 = fmaf(hh, wq.x, f0);
            f1 = fmaf(hh, wq.y, f1);
            f2 = fmaf(hh, wq.z, f2);
        }
#pragma unroll
        for (int k = 0; k < 32; ++k) {
            const float hh = __shfl(h1b, k, 32);
            const float4 wq = ws2p[32 + k][u];
            f0 = fmaf(hh, wq.x, f0);
            f1 = fmaf(hh, wq.y, f1);
            f2 = fmaf(hh, wq.z, f2);
        }
        f0 = f0 / (1.0f + __expf(-f0));
        f1 = f1 / (1.0f + __expf(-f1));
        f2 = f2 / (1.0f + __expf(-f2));

        // per-channel mixing: 4 b128 reads per k (1 per-lane + 3 uniform)
        float m0 = 0, ma0 = 0, ma1 = 0, ma2 = 0;
        float ms00 = 0, ms01 = 0, ms02 = 0, ms11 = 0, ms12 = 0, ms22 = 0;
#pragma unroll
        for (int k = 0; k < 32; ++k) {
            const float4 w  = wtp[k][u];
            const float4 q0 = accS4[hw][k][0];
            const float4 q1 = accS4[hw][k][1];
            const float4 q2 = accS4[hw][k][2];
            m0   = fmaf(q0.x, w.x, m0);
            ma0  = fmaf(q0.y, w.y, ma0);
            ma1  = fmaf(q0.z, w.y, ma1);
            ma2  = fmaf(q0.w, w.y, ma2);
            ms00 = fmaf(q1.x, w.z, ms00);
            ms01 = fmaf(q1.y, w.z, ms01);
            ms02 = fmaf(q1.z, w.z, ms02);
            ms11 = fmaf(q1.w, w.z, ms11);
            ms12 = fmaf(q2.x, w.z, ms12);
            ms22 = fmaf(q2.y, w.z, ms22);
        }

        float* xp = xout + (size_t)n * 288 + u * 9;
        xp[0] = f0 * m0 + f2 * ms00;
        xp[1] = f1 * (-ma2) + f2 * ms01;
        xp[2] = f1 * ( ma1) + f2 * ms02;
        xp[3] = f1 * ( ma2) + f2 * ms01;
        xp[4] = f0 * m0 + f2 * ms11;
        xp[5] = f1 * (-ma0) + f2 * ms12;
        xp[6] = f1 * (-ma1) + f2 * ms02;
        xp[7] = f1 * ( ma0) + f2 * ms12;
        xp[8] = f0 * m0 + f2 * ms22;
    }
}

extern "C" void kernel_launch(void* const* d_in, const int* in_sizes, int n_in,
                              void* d_out, int out_size, void* d_ws, size_t ws_size,
                              hipStream_t stream) {
    const int N = in_sizes[0];
    const int E = in_sizes[2];

    // Workspace layout (fp32): acc N*320 | P1 N*32 | P2 N*32 | Pt1 95*32 | Pt2 95*32
    float* acc = (float*)d_ws;
    float* P1  = acc + (size_t)N * 320;
    float* P2  = P1 + (size_t)N * 32;
    float* Pt1 = P2 + (size_t)N * 32;
    float* Pt2 = Pt1 + 95 * 32;

    float* xout  = (float*)d_out;              // [N][32][3][3] f32
    float* efeat = xout + (size_t)N * 288;     // [E][32] f32

    ptype_kernel<<<12, 256, 0, stream>>>(
        (const float*)d_in[6], (const float*)d_in[13], (const float*)d_in[14], Pt1, Pt2);

    prep_zero<<<(N * 320 + 255) / 256, 256, 0, stream>>>(
        (const int*)d_in[0], Pt1, Pt2, acc, P1, P2, N);

    edge_kernel<<<768, 256, 0, stream>>>(
        (const float*)d_in[1], (const float*)d_in[2], (const float*)d_in[3],
        (const int*)d_in[4], (const int*)d_in[5],
        (const float*)d_in[7],  (const float*)d_in[8],
        (const float*)d_in[9],  (const float*)d_in[10],
        (const float*)d_in[11], (const float*)d_in[12],
        (const float*)d_in[15], (const float*)d_in[16],
        P1, P2, acc, efeat, E);

    node_kernel<<<512, 256, 0, stream>>>(
        acc,
        (const float*)d_in[17], (const float*)d_in[18], (const float*)d_in[19],
        (const float*)d_in[20], (const float*)d_in[21],
        (const float*)d_in[22], (const float*)d_in[23],
        (const float*)d_in[24], (const float*)d_in[25],
        xout, N);
}